// Round 1
// baseline (546.189 us; speedup 1.0000x reference)
//
#include <hip/hip_runtime.h>
#include <hip/hip_bf16.h>

// FlyLoRALinear: out = (topk8-mask(|x@A^T + d|) * (x@A^T)) @ B^T * 2
// x:[4,4096,4096]f32  A:[32,4096]f32  B:[4096,32]f32  d:[32]f32  out:[4,4096,4096]f32
#define IN_F   4096
#define RDIM   32
#define KSEL   8
#define OUT_F  4096

typedef float  f4 __attribute__((ext_vector_type(4)));
typedef short  s8 __attribute__((ext_vector_type(8)));   // bf16x8 MFMA frag (4 VGPRs)
typedef float  cf4 __attribute__((ext_vector_type(4)));  // MFMA accum

__device__ inline short f2bf(float f) {
  __hip_bfloat16 h = __float2bfloat16(f);
  return *reinterpret_cast<short*>(&h);
}

// ---------------- k0: B fp32 -> bf16 (4096x32 = 131072 elems, 8/thread) -----
__global__ __launch_bounds__(256) void k0_convB(const float* __restrict__ B,
                                                short* __restrict__ Bb) {
  int idx = blockIdx.x * 256 + threadIdx.x;     // 0..16383
  const f4* p = (const f4*)(B + (size_t)idx * 8);
  f4 v0 = p[0], v1 = p[1];
  s8 o;
  o[0] = f2bf(v0.x); o[1] = f2bf(v0.y); o[2] = f2bf(v0.z); o[3] = f2bf(v0.w);
  o[4] = f2bf(v1.x); o[5] = f2bf(v1.y); o[6] = f2bf(v1.z); o[7] = f2bf(v1.w);
  *(s8*)(Bb + (size_t)idx * 8) = o;
}

// ---------------- k1: y = x@A^T (fp32 FMA, fp64 reduce), top-8 mask, Z bf16 --
// 2048 WGs x 256 thr. WG = 8 tokens. Wave w owns r = 8w..8w+7; lanes split K.
// X staged through LDS in 512-float chunks (read once from HBM, 4x reuse).
// A read direct from global (L2-hot: 512 KB, 512 KB/WG -> ~1 GB L2 traffic).
__global__ __launch_bounds__(256, 2) void k1_proj_topk(
    const float* __restrict__ x, const float* __restrict__ A,
    const float* __restrict__ dbias, short* __restrict__ Z)
{
  // xs[8][512] (4096 floats) aliased with red[4 waves][32 accs][66] (8448 floats)
  __shared__ __align__(16) float smem[8448];
  __shared__ double score[8][RDIM];
  __shared__ float  yval[8][RDIM];

  const int tid  = threadIdx.x;
  const int lane = tid & 63;
  const int w    = tid >> 6;
  const int m0   = blockIdx.x * 8;

  float acc[8][8];
  #pragma unroll
  for (int t = 0; t < 8; ++t)
    #pragma unroll
    for (int j = 0; j < 8; ++j) acc[t][j] = 0.f;

  const float* Abase = A + (size_t)(8 * w) * IN_F;

  for (int c = 0; c < 8; ++c) {
    const int kbase = c * 512;
    __syncthreads();                       // previous chunk fully consumed
    #pragma unroll
    for (int rep = 0; rep < 4; ++rep) {    // stage x[8 tok][512 k] = 16 KB
      int flat = rep * 256 + tid;
      int t    = flat >> 7;
      int pos  = (flat & 127) << 2;
      f4 v = __builtin_nontemporal_load(
          (const f4*)(x + (size_t)(m0 + t) * IN_F + kbase + pos));
      *(f4*)&smem[t * 512 + pos] = v;
    }
    __syncthreads();
    #pragma unroll
    for (int i = 0; i < 2; ++i) {
      const int kk = 256 * i + 4 * lane;
      f4 av[8];
      #pragma unroll
      for (int j = 0; j < 8; ++j)
        av[j] = *(const f4*)(Abase + (size_t)j * IN_F + kbase + kk);
      #pragma unroll
      for (int t = 0; t < 8; ++t) {
        f4 xv = *(const f4*)&smem[t * 512 + kk];
        #pragma unroll
        for (int j = 0; j < 8; ++j) {
          acc[t][j] = fmaf(xv.x, av[j].x, acc[t][j]);
          acc[t][j] = fmaf(xv.y, av[j].y, acc[t][j]);
          acc[t][j] = fmaf(xv.z, av[j].z, acc[t][j]);
          acc[t][j] = fmaf(xv.w, av[j].w, acc[t][j]);
        }
      }
    }
  }
  __syncthreads();                         // xs dead; alias as reduction scratch

  // Cross-lane reduce: 64 accs/lane over 64 lanes, 2 rounds of 32 accs.
  // Stride 66 floats: bank = 2a%32 -> 2-way (free). Final sum in fp64 so the
  // top-k ordering matches an exact reference (selection flips are fatal).
  float* red = smem + w * 2112;            // 32*66 floats per wave
  #pragma unroll
  for (int h = 0; h < 2; ++h) {
    #pragma unroll
    for (int a = 0; a < 32; ++a)
      red[a * 66 + lane] = acc[4 * h + (a >> 3)][a & 7];
    __syncthreads();
    if (lane < 32) {
      double s = 0.0;
      #pragma unroll
      for (int m = 0; m < 64; ++m) s += (double)red[lane * 66 + m];
      int t = 4 * h + (lane >> 3);
      int r = 8 * w + (lane & 7);
      double b = s + (double)dbias[r];
      score[t][r] = fabs(b);
      yval[t][r]  = (float)s;
    }
    __syncthreads();
  }

  // Rank-based top-8 (== jax.lax.top_k incl. tie-break to lower index).
  {
    int t = tid >> 5, i = tid & 31;
    double si = score[t][i];
    int rank = 0;
    #pragma unroll
    for (int j = 0; j < RDIM; ++j) {
      double sj = score[t][j];
      rank += (sj > si) || (sj == si && j < i);
    }
    float z = (rank < KSEL) ? yval[t][i] * 2.0f : 0.0f;   // fold SCALE=2 into Z
    Z[(size_t)(m0 + t) * RDIM + i] = f2bf(z);
  }
}

// ---------------- k2: out = Z @ Bb^T via mfma_f32_16x16x32_bf16 -------------
// Grid 4096: blockIdx = m_blk(256) + 256*n_blk(16). WG: 4 waves x 16 tokens,
// 256 o-cols. K=32 = one MFMA step. Write-bound (256 MB fp32 out).
__global__ __launch_bounds__(256, 4) void k2_lora_gemm(
    const short* __restrict__ Z, const short* __restrict__ Bb,
    float* __restrict__ out)
{
  const int tid  = threadIdx.x;
  const int lane = tid & 63;
  const int w    = tid >> 6;
  const int mb   = blockIdx.x & 255;
  const int nb   = blockIdx.x >> 8;
  const int m0   = mb * 64 + w * 16;
  const int n0   = nb * 256;
  const int rr   = lane & 15;    // frag row (A: token, B: o-col); D col
  const int q    = lane >> 4;    // k-block 8*q..8*q+7

  // A frag: Z[m0+rr][8q..8q+8) — 16 B/lane, contiguous 1 KB/wave
  s8 a = *(const s8*)(Z + (size_t)(m0 + rr) * RDIM + q * 8);
  const short* Bp = Bb + (size_t)(n0 + rr) * RDIM + q * 8;
  float* op = out + (size_t)(m0 + q * 4) * OUT_F + n0 + rr;

  #pragma unroll
  for (int tile = 0; tile < 16; ++tile) {
    s8 b = *(const s8*)(Bp + (size_t)tile * 16 * RDIM);
    cf4 d = {0.f, 0.f, 0.f, 0.f};
    d = __builtin_amdgcn_mfma_f32_16x16x32_bf16(a, b, d, 0, 0, 0);
    // D: col = lane&15 (o), row = 4q+reg (token)  [guide §3, m89-verified]
    #pragma unroll
    for (int reg = 0; reg < 4; ++reg)
      __builtin_nontemporal_store(d[reg], op + (size_t)reg * OUT_F + tile * 16);
  }
}

extern "C" void kernel_launch(void* const* d_in, const int* in_sizes, int n_in,
                              void* d_out, int out_size, void* d_ws, size_t ws_size,
                              hipStream_t stream) {
  const float* x     = (const float*)d_in[0];
  const float* A     = (const float*)d_in[1];
  const float* B     = (const float*)d_in[2];
  const float* dbias = (const float*)d_in[3];
  float* out = (float*)d_out;

  short* Z  = (short*)d_ws;                          // 16384*32 bf16 = 1 MB
  short* Bb = (short*)((char*)d_ws + (1u << 20));    // 4096*32 bf16 = 256 KB

  hipLaunchKernelGGL(k0_convB,     dim3(64),   dim3(256), 0, stream, B, Bb);
  hipLaunchKernelGGL(k1_proj_topk, dim3(2048), dim3(256), 0, stream, x, A, dbias, Z);
  hipLaunchKernelGGL(k2_lora_gemm, dim3(4096), dim3(256), 0, stream, Z, Bb, out);
}